// Round 1
// baseline (3114.179 us; speedup 1.0000x reference)
//
#include <hip/hip_runtime.h>

#define N_NODES 50000
#define E_EDGES 800000
#define D_OUT   64
#define COMB    144

// ---------------------------------------------------------------------------
// Edge kernel: one wave (64 lanes) per edge. lane = output channel d.
//   feat = [x[src] (64) | x[dst] (64) | edge_attr (16)]  staged in LDS
//   k = resstack_k(feat), v = resstack_v(feat)           (per-lane channel)
//   score[h] = (q_h . k_h)/sqrt(8)  via shfl_xor within 8-lane head groups
//   atomically accumulate  num[dst,d] += e^s * v[d],  den[dst,h] += e^s
// ---------------------------------------------------------------------------
__global__ __launch_bounds__(256) void edge_kernel(
    const float* __restrict__ x,
    const float* __restrict__ edge_attr,
    const int*   __restrict__ edge_index,
    const float* __restrict__ q,
    const float* __restrict__ kW0, const float* __restrict__ kb0,
    const float* __restrict__ kW1, const float* __restrict__ kb1,
    const float* __restrict__ kW2, const float* __restrict__ kb2,
    const float* __restrict__ vW0, const float* __restrict__ vb0,
    const float* __restrict__ vW1, const float* __restrict__ vb1,
    const float* __restrict__ vW2, const float* __restrict__ vb2,
    float* __restrict__ num,   // N*64, pre-zeroed
    float* __restrict__ den)   // N*8,  pre-zeroed
{
    __shared__ __align__(16) float feat_s[4][COMB];
    __shared__ __align__(16) float A_s[4][D_OUT];
    __shared__ __align__(16) float B_s[4][D_OUT];

    const int w    = threadIdx.x >> 6;
    const int lane = threadIdx.x & 63;
    const int e    = blockIdx.x * 4 + w;          // grid is exactly E/4

    const int src = edge_index[e];
    const int dst = edge_index[E_EDGES + e];

    // ---- stage feat (coalesced) ----
    feat_s[w][lane]      = x[(size_t)src * 64 + lane];
    feat_s[w][64 + lane] = x[(size_t)dst * 64 + lane];
    if (lane < 16) feat_s[w][128 + lane] = edge_attr[(size_t)e * 16 + lane];
    __syncthreads();

    // ================= K stack =================
    float acc = kb0[lane];
    #pragma unroll 4
    for (int i = 0; i < COMB; i += 4) {
        float4 f = *(const float4*)&feat_s[w][i];
        acc = fmaf(f.x, kW0[(i + 0) * 64 + lane], acc);
        acc = fmaf(f.y, kW0[(i + 1) * 64 + lane], acc);
        acc = fmaf(f.z, kW0[(i + 2) * 64 + lane], acc);
        acc = fmaf(f.w, kW0[(i + 3) * 64 + lane], acc);
    }
    float h0 = fmaxf(acc, 0.f);
    A_s[w][lane] = h0;
    __syncthreads();

    acc = kb1[lane] + h0;
    #pragma unroll 4
    for (int i = 0; i < D_OUT; i += 4) {
        float4 f = *(const float4*)&A_s[w][i];
        acc = fmaf(f.x, kW1[(i + 0) * 64 + lane], acc);
        acc = fmaf(f.y, kW1[(i + 1) * 64 + lane], acc);
        acc = fmaf(f.z, kW1[(i + 2) * 64 + lane], acc);
        acc = fmaf(f.w, kW1[(i + 3) * 64 + lane], acc);
    }
    float h1 = fmaxf(acc, 0.f);
    B_s[w][lane] = h1;
    __syncthreads();

    acc = kb2[lane] + h1;
    #pragma unroll 4
    for (int i = 0; i < D_OUT; i += 4) {
        float4 f = *(const float4*)&B_s[w][i];
        acc = fmaf(f.x, kW2[(i + 0) * 64 + lane], acc);
        acc = fmaf(f.y, kW2[(i + 1) * 64 + lane], acc);
        acc = fmaf(f.z, kW2[(i + 2) * 64 + lane], acc);
        acc = fmaf(f.w, kW2[(i + 3) * 64 + lane], acc);
    }
    const float kk = acc;                          // no final relu

    // ================= V stack (feat_s untouched) =================
    acc = vb0[lane];
    #pragma unroll 4
    for (int i = 0; i < COMB; i += 4) {
        float4 f = *(const float4*)&feat_s[w][i];
        acc = fmaf(f.x, vW0[(i + 0) * 64 + lane], acc);
        acc = fmaf(f.y, vW0[(i + 1) * 64 + lane], acc);
        acc = fmaf(f.z, vW0[(i + 2) * 64 + lane], acc);
        acc = fmaf(f.w, vW0[(i + 3) * 64 + lane], acc);
    }
    float g0 = fmaxf(acc, 0.f);
    A_s[w][lane] = g0;           // A_s readers finished before previous barrier
    __syncthreads();

    acc = vb1[lane] + g0;
    #pragma unroll 4
    for (int i = 0; i < D_OUT; i += 4) {
        float4 f = *(const float4*)&A_s[w][i];
        acc = fmaf(f.x, vW1[(i + 0) * 64 + lane], acc);
        acc = fmaf(f.y, vW1[(i + 1) * 64 + lane], acc);
        acc = fmaf(f.z, vW1[(i + 2) * 64 + lane], acc);
        acc = fmaf(f.w, vW1[(i + 3) * 64 + lane], acc);
    }
    float g1 = fmaxf(acc, 0.f);
    B_s[w][lane] = g1;
    __syncthreads();

    acc = vb2[lane] + g1;
    #pragma unroll 4
    for (int i = 0; i < D_OUT; i += 4) {
        float4 f = *(const float4*)&B_s[w][i];
        acc = fmaf(f.x, vW2[(i + 0) * 64 + lane], acc);
        acc = fmaf(f.y, vW2[(i + 1) * 64 + lane], acc);
        acc = fmaf(f.z, vW2[(i + 2) * 64 + lane], acc);
        acc = fmaf(f.w, vW2[(i + 3) * 64 + lane], acc);
    }
    const float vv = acc;                          // no final relu

    // ================= attention score + atomic scatter =================
    float p = q[lane] * kk;
    p += __shfl_xor(p, 1);
    p += __shfl_xor(p, 2);
    p += __shfl_xor(p, 4);                         // sum within 8-lane head
    const float score = p * 0.35355339059327373f;  // 1/sqrt(8)
    const float ex = expf(score);                  // softmax shift dropped: scores O(1)

    atomicAdd(&num[(size_t)dst * 64 + lane], ex * vv);
    if ((lane & 7) == 0)
        atomicAdd(&den[(size_t)dst * 8 + (lane >> 3)], ex);
}

// ---------------------------------------------------------------------------
// Node kernel: one wave per node. aggr = num/den -> relu -> out-stack ->
// skip-add x -> relu.
// ---------------------------------------------------------------------------
__global__ __launch_bounds__(256) void node_kernel(
    const float* __restrict__ x,
    const float* __restrict__ num,
    const float* __restrict__ den,
    const float* __restrict__ oW0, const float* __restrict__ ob0,
    const float* __restrict__ oW1, const float* __restrict__ ob1,
    const float* __restrict__ oW2, const float* __restrict__ ob2,
    float* __restrict__ out)
{
    __shared__ __align__(16) float A_s[4][D_OUT];
    __shared__ __align__(16) float B_s[4][D_OUT];

    const int w    = threadIdx.x >> 6;
    const int lane = threadIdx.x & 63;
    const int n    = blockIdx.x * 4 + w;          // grid is exactly N/4

    const float dh  = den[(size_t)n * 8 + (lane >> 3)];
    const float raw = num[(size_t)n * 64 + lane];
    float a = (dh > 0.f) ? (raw / dh) : 0.f;      // isolated node -> 0
    a = fmaxf(a, 0.f);                            // relu(aggr)
    A_s[w][lane] = a;
    __syncthreads();

    float acc = ob0[lane];
    #pragma unroll 4
    for (int i = 0; i < D_OUT; i += 4) {
        float4 f = *(const float4*)&A_s[w][i];
        acc = fmaf(f.x, oW0[(i + 0) * 64 + lane], acc);
        acc = fmaf(f.y, oW0[(i + 1) * 64 + lane], acc);
        acc = fmaf(f.z, oW0[(i + 2) * 64 + lane], acc);
        acc = fmaf(f.w, oW0[(i + 3) * 64 + lane], acc);
    }
    float h0 = fmaxf(acc, 0.f);
    B_s[w][lane] = h0;
    __syncthreads();

    acc = ob1[lane] + h0;
    #pragma unroll 4
    for (int i = 0; i < D_OUT; i += 4) {
        float4 f = *(const float4*)&B_s[w][i];
        acc = fmaf(f.x, oW1[(i + 0) * 64 + lane], acc);
        acc = fmaf(f.y, oW1[(i + 1) * 64 + lane], acc);
        acc = fmaf(f.z, oW1[(i + 2) * 64 + lane], acc);
        acc = fmaf(f.w, oW1[(i + 3) * 64 + lane], acc);
    }
    float h1 = fmaxf(acc, 0.f);
    A_s[w][lane] = h1;
    __syncthreads();

    acc = ob2[lane] + h1;
    #pragma unroll 4
    for (int i = 0; i < D_OUT; i += 4) {
        float4 f = *(const float4*)&A_s[w][i];
        acc = fmaf(f.x, oW2[(i + 0) * 64 + lane], acc);
        acc = fmaf(f.y, oW2[(i + 1) * 64 + lane], acc);
        acc = fmaf(f.z, oW2[(i + 2) * 64 + lane], acc);
        acc = fmaf(f.w, oW2[(i + 3) * 64 + lane], acc);
    }
    const float o = acc;                           // no relu on last layer

    out[(size_t)n * 64 + lane] = fmaxf(x[(size_t)n * 64 + lane] + o, 0.f);
}

extern "C" void kernel_launch(void* const* d_in, const int* in_sizes, int n_in,
                              void* d_out, int out_size, void* d_ws, size_t ws_size,
                              hipStream_t stream) {
    const float* x  = (const float*)d_in[0];
    const float* ea = (const float*)d_in[1];
    const int*   ei = (const int*)d_in[2];
    const float* q  = (const float*)d_in[3];
    const float* kW0 = (const float*)d_in[4];  const float* kb0 = (const float*)d_in[5];
    const float* kW1 = (const float*)d_in[6];  const float* kb1 = (const float*)d_in[7];
    const float* kW2 = (const float*)d_in[8];  const float* kb2 = (const float*)d_in[9];
    const float* vW0 = (const float*)d_in[10]; const float* vb0 = (const float*)d_in[11];
    const float* vW1 = (const float*)d_in[12]; const float* vb1 = (const float*)d_in[13];
    const float* vW2 = (const float*)d_in[14]; const float* vb2 = (const float*)d_in[15];
    const float* oW0 = (const float*)d_in[16]; const float* ob0 = (const float*)d_in[17];
    const float* oW1 = (const float*)d_in[18]; const float* ob1 = (const float*)d_in[19];
    const float* oW2 = (const float*)d_in[20]; const float* ob2 = (const float*)d_in[21];

    float* num = (float*)d_ws;                                   // N*64
    float* den = (float*)((char*)d_ws + (size_t)N_NODES * 64 * sizeof(float)); // N*8

    // zero the accumulators every call (harness poisons ws once, never restores)
    hipMemsetAsync(d_ws, 0, (size_t)N_NODES * (64 + 8) * sizeof(float), stream);

    edge_kernel<<<E_EDGES / 4, 256, 0, stream>>>(
        x, ea, ei, q,
        kW0, kb0, kW1, kb1, kW2, kb2,
        vW0, vb0, vW1, vb1, vW2, vb2,
        num, den);

    node_kernel<<<N_NODES / 4, 256, 0, stream>>>(
        x, num, den, oW0, ob0, oW1, ob1, oW2, ob2, (float*)d_out);
}

// Round 2
// 560.127 us; speedup vs baseline: 5.5598x; 5.5598x over previous
//
#include <hip/hip_runtime.h>

#define N_NODES 50000
#define E_EDGES 800000
#define D_OUT   64
#define COMB    144   // 64 + 64 + 16

typedef float  f32x4  __attribute__((ext_vector_type(4)));
typedef __bf16 bf16x8 __attribute__((ext_vector_type(8)));
typedef __bf16 bf16x4 __attribute__((ext_vector_type(4)));

// workspace layout (bytes):
//   [0, 12.8MB)            num  : N*64 f32 atomics
//   [12.8MB, 14.4MB)       den  : N*8  f32 atomics
//   [14.4MB, +107.5KB)     bf16 transposed+padded weights:
//     kW0t[64][168], vW0t[64][168], then 7x [64][72]:
//     kW1t,kW2t,vW1t,vW2t,oW0t,oW1t,oW2t
#define WS_NUM_OFF   0
#define WS_DEN_OFF   (12800000)
#define WS_WTS_OFF   (14400000)
#define BIG_ELEMS    (64*168)   // 10752
#define SMALL_ELEMS  (64*72)    // 4608

// ---------------------------------------------------------------------------
// prep: convert fp32 [K][64] weights to bf16 transposed [64][Kpad] (zero pad)
// ---------------------------------------------------------------------------
__global__ __launch_bounds__(256) void prep_kernel(
    const float* __restrict__ kW0, const float* __restrict__ kW1, const float* __restrict__ kW2,
    const float* __restrict__ vW0, const float* __restrict__ vW1, const float* __restrict__ vW2,
    const float* __restrict__ oW0, const float* __restrict__ oW1, const float* __restrict__ oW2,
    __bf16* __restrict__ wout)
{
    const int b = blockIdx.x, tid = threadIdx.x;
    const float* src;
    __bf16* dst;
    int K, Kpad, lb;
    if (b < 42)      { src = kW0; dst = wout;             K = 144; Kpad = 168; lb = b; }
    else if (b < 84) { src = vW0; dst = wout + BIG_ELEMS; K = 144; Kpad = 168; lb = b - 42; }
    else {
        const int id = (b - 84) / 18; lb = (b - 84) % 18;
        const float* s7[7] = {kW1, kW2, vW1, vW2, oW0, oW1, oW2};
        src = s7[id]; dst = wout + 2 * BIG_ELEMS + id * SMALL_ELEMS;
        K = 64; Kpad = 72;
    }
    const int idx = lb * 256 + tid;          // == col*Kpad + k  (exact coverage)
    const int col = idx / Kpad, k = idx % Kpad;
    dst[idx] = (k < K) ? (__bf16)src[k * 64 + col] : (__bf16)0.f;
}

// ---------------------------------------------------------------------------
// MFMA helpers. Fragment convention (both operands use the SAME contiguous
// k = hi*8+i placement, so any HW k-permutation cancels):
//   A: lane holds A[row=lane&15][k = (lane>>4)*8 + i]      (bf16x8, ds_read_b128)
//   B: lane holds B[k = (lane>>4)*8 + i][col=lane&15]  <- read from Wt[col][k]
//   D: d[r] = D[row=(lane>>4)*4 + r][col=lane&15]          (verified layout)
// ---------------------------------------------------------------------------
__device__ __forceinline__ void gemm64(const __bf16* Arow, const __bf16* Wt,
                                       int hi, int row16, f32x4 acc[4])
{
    #pragma unroll
    for (int kc = 0; kc < 2; ++kc) {
        const bf16x8 a = *(const bf16x8*)(Arow + kc * 32 + hi * 8);
        #pragma unroll
        for (int n = 0; n < 4; ++n) {
            const bf16x8 bfr = *(const bf16x8*)(Wt + (n * 16 + row16) * 72 + kc * 32 + hi * 8);
            acc[n] = __builtin_amdgcn_mfma_f32_16x16x32_bf16(a, bfr, acc[n], 0, 0, 0);
        }
    }
}

// ---------------------------------------------------------------------------
// Edge kernel: block = 64 edges, 4 waves; wave w owns edge rows w*16..w*16+15.
// ---------------------------------------------------------------------------
__global__ __launch_bounds__(256) void edge_kernel(
    const float* __restrict__ x,
    const float* __restrict__ edge_attr,
    const int*   __restrict__ edge_index,
    const float* __restrict__ q,
    const float* __restrict__ kb0, const float* __restrict__ kb1, const float* __restrict__ kb2,
    const float* __restrict__ vb0, const float* __restrict__ vb1, const float* __restrict__ vb2,
    const __bf16* __restrict__ kW0t, const __bf16* __restrict__ kW1t, const __bf16* __restrict__ kW2t,
    const __bf16* __restrict__ vW0t, const __bf16* __restrict__ vW1t, const __bf16* __restrict__ vW2t,
    float* __restrict__ num, float* __restrict__ den)
{
    __shared__ __bf16 feat_s[64][168];   // [edge][k], k 144..167 zero
    __shared__ __bf16 H0_s[64][72];
    __shared__ __bf16 H1_s[64][72];
    __shared__ int src_s[64], dst_s[64];

    const int tid  = threadIdx.x;
    const int lane = tid & 63;
    const int w    = tid >> 6;
    const int e0   = blockIdx.x * 64;
    const int row16 = lane & 15;
    const int hi    = lane >> 4;

    if (tid < 64) { src_s[tid] = edge_index[e0 + tid]; dst_s[tid] = edge_index[E_EDGES + e0 + tid]; }
    __syncthreads();

    // --- gather feat (fp32 float4 -> bf16x4 LDS) ---
    for (int i = tid; i < 64 * 36; i += 256) {
        const int r = i / 36, j = i % 36;
        float4 f;
        if (j < 16)      f = *(const float4*)&x[(size_t)src_s[r] * 64 + j * 4];
        else if (j < 32) f = *(const float4*)&x[(size_t)dst_s[r] * 64 + (j - 16) * 4];
        else             f = *(const float4*)&edge_attr[(size_t)(e0 + r) * 16 + (j - 32) * 4];
        bf16x4 h; h[0] = (__bf16)f.x; h[1] = (__bf16)f.y; h[2] = (__bf16)f.z; h[3] = (__bf16)f.w;
        *(bf16x4*)&feat_s[r][j * 4] = h;
    }
    for (int i = tid; i < 64 * 6; i += 256) {             // zero pad k = 144..167
        bf16x4 z; z[0] = z[1] = z[2] = z[3] = (__bf16)0.f;
        *(bf16x4*)&feat_s[i / 6][144 + (i % 6) * 4] = z;
    }
    __syncthreads();

    const __bf16* frow = &feat_s[w * 16 + row16][0];
    const __bf16* hrow0 = &H0_s[w * 16 + row16][0];
    const __bf16* hrow1 = &H1_s[w * 16 + row16][0];

    float kk[4][4], vv[4][4];

    #pragma unroll
    for (int stack = 0; stack < 2; ++stack) {
        const __bf16* W0t = stack == 0 ? kW0t : vW0t;
        const __bf16* W1t = stack == 0 ? kW1t : vW1t;
        const __bf16* W2t = stack == 0 ? kW2t : vW2t;
        const float*  b0  = stack == 0 ? kb0 : vb0;
        const float*  b1  = stack == 0 ? kb1 : vb1;
        const float*  b2  = stack == 0 ? kb2 : vb2;

        // layer 0: K = 160 (144 + zero pad)
        f32x4 acc[4] = {{0,0,0,0},{0,0,0,0},{0,0,0,0},{0,0,0,0}};
        #pragma unroll
        for (int kc = 0; kc < 5; ++kc) {
            const bf16x8 a = *(const bf16x8*)(frow + kc * 32 + hi * 8);
            #pragma unroll
            for (int n = 0; n < 4; ++n) {
                const bf16x8 bfr = *(const bf16x8*)(W0t + (n * 16 + row16) * 168 + kc * 32 + hi * 8);
                acc[n] = __builtin_amdgcn_mfma_f32_16x16x32_bf16(a, bfr, acc[n], 0, 0, 0);
            }
        }
        float h0[4][4];
        #pragma unroll
        for (int n = 0; n < 4; ++n) {
            const float bias = b0[n * 16 + row16];
            #pragma unroll
            for (int r = 0; r < 4; ++r) {
                h0[n][r] = fmaxf(acc[n][r] + bias, 0.f);
                H0_s[w * 16 + hi * 4 + r][n * 16 + row16] = (__bf16)h0[n][r];
            }
        }

        // layer 1: h1 = relu(h0 + h0@W1 + b1)
        f32x4 acc1[4] = {{0,0,0,0},{0,0,0,0},{0,0,0,0},{0,0,0,0}};
        gemm64(hrow0, W1t, hi, row16, acc1);
        float h1[4][4];
        #pragma unroll
        for (int n = 0; n < 4; ++n) {
            const float bias = b1[n * 16 + row16];
            #pragma unroll
            for (int r = 0; r < 4; ++r) {
                h1[n][r] = fmaxf(h0[n][r] + acc1[n][r] + bias, 0.f);
                H1_s[w * 16 + hi * 4 + r][n * 16 + row16] = (__bf16)h1[n][r];
            }
        }

        // layer 2: out = h1 + h1@W2 + b2   (no relu)
        f32x4 acc2[4] = {{0,0,0,0},{0,0,0,0},{0,0,0,0},{0,0,0,0}};
        gemm64(hrow1, W2t, hi, row16, acc2);
        #pragma unroll
        for (int n = 0; n < 4; ++n) {
            const float bias = b2[n * 16 + row16];
            #pragma unroll
            for (int r = 0; r < 4; ++r) {
                const float o = h1[n][r] + acc2[n][r] + bias;
                if (stack == 0) kk[n][r] = o; else vv[n][r] = o;
            }
        }
    }

    // --- attention scores: head h = 2n + bit3, bit3 = row16>>3 ---
    float qv[4];
    #pragma unroll
    for (int n = 0; n < 4; ++n) qv[n] = q[n * 16 + row16];

    float ex[4][4];
    #pragma unroll
    for (int n = 0; n < 4; ++n)
        #pragma unroll
        for (int r = 0; r < 4; ++r) {
            float p = qv[n] * kk[n][r];
            p += __shfl_xor(p, 1);
            p += __shfl_xor(p, 2);
            p += __shfl_xor(p, 4);                      // sum over the 8 lanes of this head
            ex[n][r] = __expf(p * 0.35355339059327373f); // softmax shift dropped: scores O(1)
        }

    const int b3 = row16 >> 3;
    #pragma unroll
    for (int r = 0; r < 4; ++r) {
        const int drow = dst_s[w * 16 + hi * 4 + r];
        if ((lane & 7) == 0) {
            #pragma unroll
            for (int n = 0; n < 4; ++n)
                atomicAdd(&den[(size_t)drow * 8 + 2 * n + b3], ex[n][r]);
        }
        #pragma unroll
        for (int n = 0; n < 4; ++n)
            atomicAdd(&num[(size_t)drow * 64 + n * 16 + row16], ex[n][r] * vv[n][r]);
    }
}

// ---------------------------------------------------------------------------
// Node kernel: block = 64 nodes; aggr = relu(num/den) -> out stack -> skip.
// ---------------------------------------------------------------------------
__global__ __launch_bounds__(256) void node_kernel(
    const float* __restrict__ x,
    const float* __restrict__ num, const float* __restrict__ den,
    const float* __restrict__ ob0, const float* __restrict__ ob1, const float* __restrict__ ob2,
    const __bf16* __restrict__ oW0t, const __bf16* __restrict__ oW1t, const __bf16* __restrict__ oW2t,
    float* __restrict__ out)
{
    __shared__ __bf16 A_s[64][72];
    __shared__ __bf16 H0_s[64][72];
    __shared__ __bf16 H1_s[64][72];

    const int tid  = threadIdx.x;
    const int lane = tid & 63;
    const int w    = tid >> 6;
    const int n0   = blockIdx.x * 64;
    const int row16 = lane & 15;
    const int hi    = lane >> 4;

    // stage aggr = relu(num/den) as bf16
    for (int i = tid; i < 64 * 16; i += 256) {
        const int r = i >> 4, c4 = (i & 15) * 4;
        const int node = n0 + r;
        bf16x4 h; h[0] = h[1] = h[2] = h[3] = (__bf16)0.f;
        if (node < N_NODES) {
            const float dh = den[(size_t)node * 8 + (c4 >> 3)];
            if (dh > 0.f) {
                const float4 f = *(const float4*)&num[(size_t)node * 64 + c4];
                const float inv = 1.f / dh;
                h[0] = (__bf16)fmaxf(f.x * inv, 0.f);
                h[1] = (__bf16)fmaxf(f.y * inv, 0.f);
                h[2] = (__bf16)fmaxf(f.z * inv, 0.f);
                h[3] = (__bf16)fmaxf(f.w * inv, 0.f);
            }
        }
        *(bf16x4*)&A_s[r][c4] = h;
    }
    __syncthreads();

    const __bf16* arow  = &A_s[w * 16 + row16][0];
    const __bf16* hrow0 = &H0_s[w * 16 + row16][0];
    const __bf16* hrow1 = &H1_s[w * 16 + row16][0];

    f32x4 acc[4] = {{0,0,0,0},{0,0,0,0},{0,0,0,0},{0,0,0,0}};
    gemm64(arow, oW0t, hi, row16, acc);
    float h0[4][4];
    #pragma unroll
    for (int n = 0; n < 4; ++n) {
        const float bias = ob0[n * 16 + row16];
        #pragma unroll
        for (int r = 0; r < 4; ++r) {
            h0[n][r] = fmaxf(acc[n][r] + bias, 0.f);
            H0_s[w * 16 + hi * 4 + r][n * 16 + row16] = (__bf16)h0[n][r];
        }
    }

    f32x4 acc1[4] = {{0,0,0,0},{0,0,0,0},{0,0,0,0},{0,0,0,0}};
    gemm64(hrow0, oW1t, hi, row16, acc1);
    float h1[4][4];
    #pragma unroll
    for (int n = 0; n < 4; ++n) {
        const float bias = ob1[n * 16 + row16];
        #pragma unroll
        for (int r = 0; r < 4; ++r) {
            h1[n][r] = fmaxf(h0[n][r] + acc1[n][r] + bias, 0.f);
            H1_s[w * 16 + hi * 4 + r][n * 16 + row16] = (__bf16)h1[n][r];
        }
    }

    f32x4 acc2[4] = {{0,0,0,0},{0,0,0,0},{0,0,0,0},{0,0,0,0}};
    gemm64(hrow1, oW2t, hi, row16, acc2);
    #pragma unroll
    for (int n = 0; n < 4; ++n) {
        const float bias = ob2[n * 16 + row16];
        #pragma unroll
        for (int r = 0; r < 4; ++r) {
            const int node = n0 + w * 16 + hi * 4 + r;
            if (node < N_NODES) {
                const int col = n * 16 + row16;
                const float o = h1[n][r] + acc2[n][r] + bias;
                out[(size_t)node * 64 + col] = fmaxf(x[(size_t)node * 64 + col] + o, 0.f);
            }
        }
    }
}

extern "C" void kernel_launch(void* const* d_in, const int* in_sizes, int n_in,
                              void* d_out, int out_size, void* d_ws, size_t ws_size,
                              hipStream_t stream) {
    const float* x  = (const float*)d_in[0];
    const float* ea = (const float*)d_in[1];
    const int*   ei = (const int*)d_in[2];
    const float* q  = (const float*)d_in[3];
    const float* kW0 = (const float*)d_in[4];  const float* kb0 = (const float*)d_in[5];
    const float* kW1 = (const float*)d_in[6];  const float* kb1 = (const float*)d_in[7];
    const float* kW2 = (const float*)d_in[8];  const float* kb2 = (const float*)d_in[9];
    const float* vW0 = (const float*)d_in[10]; const float* vb0 = (const float*)d_in[11];
    const float* vW1 = (const float*)d_in[12]; const float* vb1 = (const float*)d_in[13];
    const float* vW2 = (const float*)d_in[14]; const float* vb2 = (const float*)d_in[15];
    const float* oW0 = (const float*)d_in[16]; const float* ob0 = (const float*)d_in[17];
    const float* oW1 = (const float*)d_in[18]; const float* ob1 = (const float*)d_in[19];
    const float* oW2 = (const float*)d_in[20]; const float* ob2 = (const float*)d_in[21];

    char* ws = (char*)d_ws;
    float*  num  = (float*)(ws + WS_NUM_OFF);
    float*  den  = (float*)(ws + WS_DEN_OFF);
    __bf16* wts  = (__bf16*)(ws + WS_WTS_OFF);
    __bf16* kW0t = wts;
    __bf16* vW0t = wts + BIG_ELEMS;
    __bf16* sm   = wts + 2 * BIG_ELEMS;
    __bf16* kW1t = sm;                  __bf16* kW2t = sm + SMALL_ELEMS;
    __bf16* vW1t = sm + 2 * SMALL_ELEMS; __bf16* vW2t = sm + 3 * SMALL_ELEMS;
    __bf16* oW0t = sm + 4 * SMALL_ELEMS; __bf16* oW1t = sm + 5 * SMALL_ELEMS;
    __bf16* oW2t = sm + 6 * SMALL_ELEMS;

    hipMemsetAsync(d_ws, 0, (size_t)N_NODES * (64 + 8) * sizeof(float), stream);

    prep_kernel<<<210, 256, 0, stream>>>(kW0, kW1, kW2, vW0, vW1, vW2, oW0, oW1, oW2, wts);

    edge_kernel<<<E_EDGES / 64, 256, 0, stream>>>(
        x, ea, ei, q,
        kb0, kb1, kb2, vb0, vb1, vb2,
        kW0t, kW1t, kW2t, vW0t, vW1t, vW2t,
        num, den);

    node_kernel<<<(N_NODES + 63) / 64, 256, 0, stream>>>(
        x, num, den, ob0, ob1, ob2, oW0t, oW1t, oW2t, (float*)d_out);
}